// Round 2
// baseline (735.206 us; speedup 1.0000x reference)
//
#include <hip/hip_runtime.h>

#define N_PTS 100000
#define NK 27
#define TOTAL (N_PTS * 64)          // 6400000
#define NB_CONV 1563                // ceil(100000 / 64)

typedef short bf16x8 __attribute__((ext_vector_type(8)));   // 8 bf16 in 4 VGPRs
typedef float f32x4 __attribute__((ext_vector_type(4)));
typedef unsigned short u16x8 __attribute__((ext_vector_type(8)));

__device__ __forceinline__ unsigned short f2bf(float f) {
    unsigned u = __builtin_bit_cast(unsigned, f);
    u += 0x7fffu + ((u >> 16) & 1u);           // round-to-nearest-even
    return (unsigned short)(u >> 16);
}
__device__ __forceinline__ float bf2f(unsigned short u) {
    return __builtin_bit_cast(float, ((unsigned)u) << 16);
}

// ---------------- cast feats -> bf16, plus zeroed pad row at index N_PTS ----------------
__global__ void cast_in_k(const float* __restrict__ feats, unsigned short* __restrict__ xb) {
    int t = blockIdx.x * 256 + threadIdx.x;
    if (t >= (N_PTS + 1) * 8) return;          // 8-elem chunks per 64-ch row
    int i = t * 8;
    u16x8 o;
    if (i < TOTAL) {
        f32x4 v0 = ((const f32x4*)(feats + i))[0];
        f32x4 v1 = ((const f32x4*)(feats + i))[1];
#pragma unroll
        for (int j = 0; j < 4; ++j) { o[j] = f2bf(v0[j]); o[4 + j] = f2bf(v1[j]); }
    } else {
#pragma unroll
        for (int j = 0; j < 8; ++j) o[j] = 0;
    }
    *(u16x8*)(xb + i) = o;
}

// ---------------- pack W [4][27][64][64] f32 -> bf16 MFMA-B-fragment order ----------------
// Wp layout: [conv][k][kk][cb][lane][8] ; fragment elem j is B[k = kk*32+(lane>>4)*8+j, col = cb*16+(lane&15)]
__global__ void pack_w_k(const float* __restrict__ W, unsigned short* __restrict__ Wp) {
    int o = blockIdx.x * 256 + threadIdx.x;
    if (o >= 4 * NK * 4096) return;
    int conv = o / (NK * 4096);
    int r = o - conv * (NK * 4096);
    int k = r >> 12;
    int r2 = r & 4095;
    int frag = r2 >> 9;                        // kk*4 + cb
    int kk = frag >> 2, cb = frag & 3;
    int lane = (r2 >> 3) & 63;
    int j = r2 & 7;
    int c = kk * 32 + (lane >> 4) * 8 + j;
    int d = cb * 16 + (lane & 15);
    Wp[o] = f2bf(W[(size_t)(conv * NK + k) * 4096 + c * 64 + d]);
}

// ---------------- gather-GEMM conv: y[n,d] = sum_k sum_c xb[nbrs[n,k],c] * W[k,c,d] ----------------
// block = 256 thr = 4 waves; each wave owns 16 rows x 64 cols. Indices fully
// prefetched into registers; K-loop fully unrolled for deep MLP.
__global__ __launch_bounds__(256, 4) void conv_k(
    const unsigned short* __restrict__ xb,     // [N_PTS+1][64] bf16
    const int* __restrict__ nbrs,              // [N_PTS][27]
    const unsigned short* __restrict__ Wp,     // packed fragments for this conv
    unsigned short* __restrict__ ybf,          // [N_PTS][64] bf16
    float* __restrict__ partials)              // [NB_CONV][128]
{
    const int tid = threadIdx.x;
    const int lane = tid & 63;
    const int wave = tid >> 6;
    const int l15 = lane & 15;
    const int lgrp = lane >> 4;
    const int wave_row = blockIdx.x * 64 + wave * 16;

    const int r0 = wave_row + l15;
    const bool ok = r0 < N_PTS;
    const size_t n0 = (size_t)r0 * NK;

    // prefetch all rulebook indices (removes idx->gather chain from the loop)
    int idx[NK];
#pragma unroll
    for (int k = 0; k < NK; ++k) idx[k] = ok ? nbrs[n0 + k] : N_PTS;

    f32x4 acc[4];
#pragma unroll
    for (int cb = 0; cb < 4; ++cb) acc[cb] = (f32x4)0.f;

    const bf16x8* wp = (const bf16x8*)Wp;

#pragma unroll
    for (int k = 0; k < NK; ++k) {
        const bf16x8* p = (const bf16x8*)(xb + (size_t)idx[k] * 64);
        bf16x8 a0 = p[lgrp];                   // channels 0..31, lane's 8-ch slice
        bf16x8 a1 = p[4 + lgrp];               // channels 32..63
        const bf16x8* wk = wp + (size_t)k * 512 + lane;   // frag f at wk[f*64]
#pragma unroll
        for (int cb = 0; cb < 4; ++cb)
            acc[cb] = __builtin_amdgcn_mfma_f32_16x16x32_bf16(a0, wk[cb * 64], acc[cb], 0, 0, 0);
#pragma unroll
        for (int cb = 0; cb < 4; ++cb)
            acc[cb] = __builtin_amdgcn_mfma_f32_16x16x32_bf16(a1, wk[(4 + cb) * 64], acc[cb], 0, 0, 0);
    }

    // ---- store y as bf16 (D layout: col = cb*16 + (lane&15), row = lgrp*4 + reg) ----
    const int rb = wave_row + lgrp * 4;
#pragma unroll
    for (int r = 0; r < 4; ++r) {
        if (rb + r < N_PTS) {
            unsigned short* yr = ybf + (size_t)(rb + r) * 64 + l15;
#pragma unroll
            for (int cb = 0; cb < 4; ++cb) yr[cb * 16] = f2bf(acc[cb][r]);
        }
    }

    // ---- fused per-channel partial sum / sumsq (over this wave's 16 rows) ----
    __shared__ float sred[4][128];
#pragma unroll
    for (int cb = 0; cb < 4; ++cb) {
        float s = 0.f, s2 = 0.f;
#pragma unroll
        for (int r = 0; r < 4; ++r) {
            float v = acc[cb][r];
            s += v; s2 += v * v;
        }
        s += __shfl_xor(s, 16); s += __shfl_xor(s, 32);
        s2 += __shfl_xor(s2, 16); s2 += __shfl_xor(s2, 32);
        if (lane < 16) {
            sred[wave][cb * 16 + l15] = s;
            sred[wave][64 + cb * 16 + l15] = s2;
        }
    }
    __syncthreads();
    if (tid < 128) {
        float p = sred[0][tid] + sred[1][tid] + sred[2][tid] + sred[3][tid];
        partials[(size_t)blockIdx.x * 128 + tid] = p;
    }
}

// ---------------- BN finalize: scale/shift from partials ----------------
__global__ void bn_fin_k(const float* __restrict__ partials,
                         const float* __restrict__ gamma,
                         const float* __restrict__ beta,
                         float* __restrict__ scsh) {
    int t = threadIdx.x;                       // 1024 threads
    int c = t & 127, chunk = t >> 7;           // 8 chunks
    float s = 0.f;
    for (int w = chunk; w < NB_CONV; w += 8) s += partials[(size_t)w * 128 + c];
    __shared__ float sm[1024];
    sm[t] = s;
    __syncthreads();
    if (t < 128) {
        float tot = 0.f;
#pragma unroll
        for (int j = 0; j < 8; ++j) tot += sm[j * 128 + t];
        sm[t] = tot;
    }
    __syncthreads();
    if (t < 64) {
        const float invN = 1.0f / (float)N_PTS;
        float mu = sm[t] * invN;
        float var = sm[64 + t] * invN - mu * mu;
        float sc = gamma[t] * rsqrtf(var + 1e-4f);
        scsh[t] = sc;
        scsh[64 + t] = beta[t] - mu * sc;
    }
}

// ---------------- BN + ReLU -> bf16 (input to next conv) ----------------
__global__ void bn_relu_cast_k(const unsigned short* __restrict__ ybf, const float* __restrict__ scsh,
                               unsigned short* __restrict__ xb) {
    int t = blockIdx.x * 256 + threadIdx.x;
    if (t >= TOTAL / 8) return;
    int i = t * 8;
    int c0 = i & 63;
    u16x8 v = *(const u16x8*)(ybf + i);
    f32x4 sa = *(const f32x4*)(scsh + c0);
    f32x4 sb = *(const f32x4*)(scsh + c0 + 4);
    f32x4 ba = *(const f32x4*)(scsh + 64 + c0);
    f32x4 bb = *(const f32x4*)(scsh + 64 + c0 + 4);
    u16x8 o;
#pragma unroll
    for (int j = 0; j < 4; ++j) {
        o[j]     = f2bf(fmaxf(bf2f(v[j])     * sa[j] + ba[j], 0.f));
        o[4 + j] = f2bf(fmaxf(bf2f(v[4 + j]) * sb[j] + bb[j], 0.f));
    }
    *(u16x8*)(xb + i) = o;
}

// ---------------- BN + residual + ReLU -> f32 out (+ bf16 for next conv) ----------------
__global__ void bn_add_relu_k(const unsigned short* __restrict__ ybf, const float* __restrict__ scsh,
                              const float* __restrict__ res, float* __restrict__ xout,
                              unsigned short* __restrict__ xb, int writeBf) {
    int t = blockIdx.x * 256 + threadIdx.x;
    if (t >= TOTAL / 8) return;
    int i = t * 8;
    int c0 = i & 63;
    u16x8 v = *(const u16x8*)(ybf + i);
    f32x4 q0 = ((const f32x4*)(res + i))[0];
    f32x4 q1 = ((const f32x4*)(res + i))[1];
    f32x4 sa = *(const f32x4*)(scsh + c0);
    f32x4 sb = *(const f32x4*)(scsh + c0 + 4);
    f32x4 ba = *(const f32x4*)(scsh + 64 + c0);
    f32x4 bb = *(const f32x4*)(scsh + 64 + c0 + 4);
    f32x4 o0, o1;
#pragma unroll
    for (int j = 0; j < 4; ++j) {
        o0[j] = fmaxf(bf2f(v[j])     * sa[j] + ba[j] + q0[j], 0.f);
        o1[j] = fmaxf(bf2f(v[4 + j]) * sb[j] + bb[j] + q1[j], 0.f);
    }
    ((f32x4*)(xout + i))[0] = o0;
    ((f32x4*)(xout + i))[1] = o1;
    if (writeBf) {
        u16x8 o;
#pragma unroll
        for (int j = 0; j < 4; ++j) { o[j] = f2bf(o0[j]); o[4 + j] = f2bf(o1[j]); }
        *(u16x8*)(xb + i) = o;
    }
}

extern "C" void kernel_launch(void* const* d_in, const int* in_sizes, int n_in,
                              void* d_out, int out_size, void* d_ws, size_t ws_size,
                              hipStream_t stream) {
    const float* feats = (const float*)d_in[0];
    const int*   nbrs  = (const int*)d_in[1];
    const float* W     = (const float*)d_in[2];
    const float* gamma = (const float*)d_in[3];
    const float* beta  = (const float*)d_in[4];
    float* out = (float*)d_out;

    char* ws = (char*)d_ws;
    unsigned short* xb       = (unsigned short*)ws;              // 12,800,128 B
    unsigned short* ybf      = (unsigned short*)(ws + 12800512); // 12,800,000 B
    unsigned short* Wp       = (unsigned short*)(ws + 25600512); //    884,736 B
    float*          partials = (float*)(ws + 26485248);          //    800,256 B
    float*          scsh     = (float*)(ws + 27285504);          //        512 B

    dim3 b256(256);
    cast_in_k<<<((N_PTS + 1) * 8 + 255) / 256, b256, 0, stream>>>(feats, xb);
    pack_w_k<<<(4 * NK * 4096) / 256, b256, 0, stream>>>(W, Wp);

    const int appl_blocks = (TOTAL / 8) / 256;  // 3125
    for (int blk = 0; blk < 2; ++blk) {
        int c0 = blk * 2, c1 = blk * 2 + 1;
        conv_k<<<NB_CONV, b256, 0, stream>>>(xb, nbrs, Wp + (size_t)c0 * NK * 4096, ybf, partials);
        bn_fin_k<<<1, 1024, 0, stream>>>(partials, gamma + c0 * 64, beta + c0 * 64, scsh);
        bn_relu_cast_k<<<appl_blocks, b256, 0, stream>>>(ybf, scsh, xb);
        conv_k<<<NB_CONV, b256, 0, stream>>>(xb, nbrs, Wp + (size_t)c1 * NK * 4096, ybf, partials);
        bn_fin_k<<<1, 1024, 0, stream>>>(partials, gamma + c1 * 64, beta + c1 * 64, scsh);
        const float* res = (blk == 0) ? feats : (const float*)out;
        bn_add_relu_k<<<appl_blocks, b256, 0, stream>>>(ybf, scsh, res, out, xb, blk == 0 ? 1 : 0);
    }
}

// Round 4
// 470.321 us; speedup vs baseline: 1.5632x; 1.5632x over previous
//
#include <hip/hip_runtime.h>

#define N_PTS 100000
#define NT_STRIDE 100096            // padded row count for nbrsT (782*128)
#define NK 27
#define TOTAL (N_PTS * 64)          // 6400000
#define NB_CONV 782                 // grid: 782 blocks * 128 rows

typedef short bf16x8 __attribute__((ext_vector_type(8)));   // 8 bf16 in 4 VGPRs
typedef float f32x4 __attribute__((ext_vector_type(4)));
typedef unsigned short u16x8 __attribute__((ext_vector_type(8)));

__device__ __forceinline__ unsigned short f2bf(float f) {
    unsigned u = __builtin_bit_cast(unsigned, f);
    u += 0x7fffu + ((u >> 16) & 1u);           // round-to-nearest-even
    return (unsigned short)(u >> 16);
}
__device__ __forceinline__ float bf2f(unsigned short u) {
    return __builtin_bit_cast(float, ((unsigned)u) << 16);
}

// ---------------- cast feats -> bf16, plus zeroed pad row at index N_PTS ----------------
__global__ void cast_in_k(const float* __restrict__ feats, unsigned short* __restrict__ xb) {
    int t = blockIdx.x * 256 + threadIdx.x;
    if (t >= (N_PTS + 1) * 8) return;
    int i = t * 8;
    u16x8 o;
    if (i < TOTAL) {
        f32x4 v0 = ((const f32x4*)(feats + i))[0];
        f32x4 v1 = ((const f32x4*)(feats + i))[1];
#pragma unroll
        for (int j = 0; j < 4; ++j) { o[j] = f2bf(v0[j]); o[4 + j] = f2bf(v1[j]); }
    } else {
#pragma unroll
        for (int j = 0; j < 8; ++j) o[j] = 0;
    }
    *(u16x8*)(xb + i) = o;
}

// ---------------- transpose rulebook: nbrsT[k][n] = nbrs[n][k]; pad rows -> N_PTS ----------------
__global__ void tr_nbrs_k(const int* __restrict__ nbrs, int* __restrict__ nbrsT) {
    __shared__ int tile[64 * 28];
    const int n0 = blockIdx.x * 64;
    const int t = threadIdx.x;
    const int base = n0 * 27;
    for (int i = t; i < 1728; i += 256) {
        int v = (base + i < N_PTS * 27) ? nbrs[base + i] : N_PTS;
        int r = i / 27, c = i - r * 27;
        tile[r * 28 + c] = v;
    }
    __syncthreads();
    for (int i = t; i < 1728; i += 256) {
        int k = i >> 6, j = i & 63;                        // k 0..26
        nbrsT[(size_t)k * NT_STRIDE + n0 + j] = tile[j * 28 + k];
    }
}

// ---------------- pack W [4][27][64][64] f32 -> bf16 MFMA-B-fragment order ----------------
// Wp layout: [conv][k][kk][cb][lane][8]; frag elem j is B[c = kk*32+(lane>>4)*8+j, d = cb*16+(lane&15)]
__global__ void pack_w_k(const float* __restrict__ W, unsigned short* __restrict__ Wp) {
    int o = blockIdx.x * 256 + threadIdx.x;
    if (o >= 4 * NK * 4096) return;
    int conv = o / (NK * 4096);
    int r = o - conv * (NK * 4096);
    int k = r >> 12;
    int r2 = r & 4095;
    int frag = r2 >> 9;
    int kk = frag >> 2, cb = frag & 3;
    int lane = (r2 >> 3) & 63;
    int j = r2 & 7;
    int c = kk * 32 + (lane >> 4) * 8 + j;
    int d = cb * 16 + (lane & 15);
    Wp[o] = f2bf(W[(size_t)(conv * NK + k) * 4096 + c * 64 + d]);
}

// ---------------- gather-GEMM conv, software-pipelined ----------------
// 4 waves/block, wave owns 32 rows x 64 cols. idx PF distance 4 (coalesced from nbrsT),
// A-gather PF depth 2 (issue k+2 while MFMA k), B inline (L1/L2-hot).
__global__ __launch_bounds__(256, 3) void conv_k(
    const unsigned short* __restrict__ xb,     // [N_PTS+1][64] bf16
    const int* __restrict__ nbrsT,             // [27][NT_STRIDE]
    const unsigned short* __restrict__ Wp,     // packed fragments for this conv
    unsigned short* __restrict__ ybf,          // [N_PTS][64] bf16
    float* __restrict__ partials)              // [NB_CONV][128]
{
    const int tid = threadIdx.x;
    const int lane = tid & 63;
    const int wave = tid >> 6;
    const int l15 = lane & 15;
    const int lgrp = lane >> 4;
    const int wave_row = blockIdx.x * 128 + wave * 32;
    const int r0 = wave_row + l15;             // < NT_STRIDE always
    const int r1 = r0 + 16;

    f32x4 acc[2][4];
#pragma unroll
    for (int m = 0; m < 2; ++m)
#pragma unroll
        for (int cb = 0; cb < 4; ++cb) acc[m][cb] = (f32x4)0.f;

    const bf16x8* wp = (const bf16x8*)Wp;

    // idx pipeline: window of 4 (per row-half); rows >= N_PTS read padded N_PTS
    int id0[4], id1[4];
#pragma unroll
    for (int s = 0; s < 4; ++s) {
        id0[s] = nbrsT[(size_t)s * NT_STRIDE + r0];
        id1[s] = nbrsT[(size_t)s * NT_STRIDE + r1];
    }
    // A pipeline: 3 stages x 4 frags ([0]=row0 c0-31, [1]=row0 c32-63, [2]=row1 c0-31, [3]=row1 c32-63)
    bf16x8 apf[3][4];
#pragma unroll
    for (int s = 0; s < 2; ++s) {
        const bf16x8* p0 = (const bf16x8*)(xb + (size_t)id0[s] * 64);
        const bf16x8* p1 = (const bf16x8*)(xb + (size_t)id1[s] * 64);
        apf[s][0] = p0[lgrp]; apf[s][1] = p0[4 + lgrp];
        apf[s][2] = p1[lgrp]; apf[s][3] = p1[4 + lgrp];
    }

#pragma unroll
    for (int k = 0; k < NK; ++k) {
        if (k + 4 < NK) {                      // idx prefetch (coalesced 128B/row-set)
            id0[k & 3] = nbrsT[(size_t)(k + 4) * NT_STRIDE + r0];
            id1[k & 3] = nbrsT[(size_t)(k + 4) * NT_STRIDE + r1];
        }
        if (k + 2 < NK) {                      // A-gather prefetch for k+2
            const int j = (k + 2) & 3;
            const int s2 = (k + 2) % 3;
            const bf16x8* p0 = (const bf16x8*)(xb + (size_t)id0[j] * 64);
            const bf16x8* p1 = (const bf16x8*)(xb + (size_t)id1[j] * 64);
            apf[s2][0] = p0[lgrp]; apf[s2][1] = p0[4 + lgrp];
            apf[s2][2] = p1[lgrp]; apf[s2][3] = p1[4 + lgrp];
        }
        const int s = k % 3;
        const bf16x8* wk = wp + (size_t)k * 512 + lane;
        {   // kk = 0 (c 0..31)
            bf16x8 b0 = wk[0], b1 = wk[64], b2 = wk[128], b3 = wk[192];
            acc[0][0] = __builtin_amdgcn_mfma_f32_16x16x32_bf16(apf[s][0], b0, acc[0][0], 0, 0, 0);
            acc[1][0] = __builtin_amdgcn_mfma_f32_16x16x32_bf16(apf[s][2], b0, acc[1][0], 0, 0, 0);
            acc[0][1] = __builtin_amdgcn_mfma_f32_16x16x32_bf16(apf[s][0], b1, acc[0][1], 0, 0, 0);
            acc[1][1] = __builtin_amdgcn_mfma_f32_16x16x32_bf16(apf[s][2], b1, acc[1][1], 0, 0, 0);
            acc[0][2] = __builtin_amdgcn_mfma_f32_16x16x32_bf16(apf[s][0], b2, acc[0][2], 0, 0, 0);
            acc[1][2] = __builtin_amdgcn_mfma_f32_16x16x32_bf16(apf[s][2], b2, acc[1][2], 0, 0, 0);
            acc[0][3] = __builtin_amdgcn_mfma_f32_16x16x32_bf16(apf[s][0], b3, acc[0][3], 0, 0, 0);
            acc[1][3] = __builtin_amdgcn_mfma_f32_16x16x32_bf16(apf[s][2], b3, acc[1][3], 0, 0, 0);
        }
        {   // kk = 1 (c 32..63)
            bf16x8 b0 = wk[256], b1 = wk[320], b2 = wk[384], b3 = wk[448];
            acc[0][0] = __builtin_amdgcn_mfma_f32_16x16x32_bf16(apf[s][1], b0, acc[0][0], 0, 0, 0);
            acc[1][0] = __builtin_amdgcn_mfma_f32_16x16x32_bf16(apf[s][3], b0, acc[1][0], 0, 0, 0);
            acc[0][1] = __builtin_amdgcn_mfma_f32_16x16x32_bf16(apf[s][1], b1, acc[0][1], 0, 0, 0);
            acc[1][1] = __builtin_amdgcn_mfma_f32_16x16x32_bf16(apf[s][3], b1, acc[1][1], 0, 0, 0);
            acc[0][2] = __builtin_amdgcn_mfma_f32_16x16x32_bf16(apf[s][1], b2, acc[0][2], 0, 0, 0);
            acc[1][2] = __builtin_amdgcn_mfma_f32_16x16x32_bf16(apf[s][3], b2, acc[1][2], 0, 0, 0);
            acc[0][3] = __builtin_amdgcn_mfma_f32_16x16x32_bf16(apf[s][1], b3, acc[0][3], 0, 0, 0);
            acc[1][3] = __builtin_amdgcn_mfma_f32_16x16x32_bf16(apf[s][3], b3, acc[1][3], 0, 0, 0);
        }
    }

    // ---- y store via LDS transpose -> coalesced dwordx4 (stride 72 halfwords, 16B-aligned rows) ----
    __shared__ __align__(16) unsigned short yt[4][32 * 72];
    unsigned short* myt = &yt[wave][0];
#pragma unroll
    for (int m = 0; m < 2; ++m)
#pragma unroll
        for (int cb = 0; cb < 4; ++cb)
#pragma unroll
            for (int r = 0; r < 4; ++r)
                myt[(m * 16 + lgrp * 4 + r) * 72 + cb * 16 + l15] = f2bf(acc[m][cb][r]);
    // wave-local LDS (each wave touches only its own slab); in-order LDS + compiler lgkmcnt
#pragma unroll
    for (int c2 = 0; c2 < 4; ++c2) {
        int chunk = c2 * 64 + lane;            // consecutive lanes -> consecutive 16B
        int row = chunk >> 3;
        int col8 = chunk & 7;
        int grow = wave_row + row;
        if (grow < N_PTS) {
            u16x8 v = *(const u16x8*)(myt + row * 72 + col8 * 8);
            *(u16x8*)(ybf + (size_t)grow * 64 + col8 * 8) = v;
        }
    }

    // ---- fused per-channel partial sum / sumsq ----
    __shared__ float sred[4][128];
#pragma unroll
    for (int cb = 0; cb < 4; ++cb) {
        float s = 0.f, s2 = 0.f;
#pragma unroll
        for (int m = 0; m < 2; ++m)
#pragma unroll
            for (int r = 0; r < 4; ++r) {
                float v = acc[m][cb][r];
                s += v; s2 += v * v;
            }
        s += __shfl_xor(s, 16); s += __shfl_xor(s, 32);
        s2 += __shfl_xor(s2, 16); s2 += __shfl_xor(s2, 32);
        if (lane < 16) {
            sred[wave][cb * 16 + l15] = s;
            sred[wave][64 + cb * 16 + l15] = s2;
        }
    }
    __syncthreads();
    if (tid < 128) {
        float p = sred[0][tid] + sred[1][tid] + sred[2][tid] + sred[3][tid];
        partials[(size_t)blockIdx.x * 128 + tid] = p;
    }
}

// ---------------- BN finalize: 64 blocks, one channel each ----------------
__global__ void bn_fin_k(const float* __restrict__ partials,
                         const float* __restrict__ gamma,
                         const float* __restrict__ beta,
                         float* __restrict__ scsh) {
    const int c = blockIdx.x;                  // 0..63
    const int t = threadIdx.x;                 // 256
    float s = 0.f, s2 = 0.f;
    for (int w = t; w < NB_CONV; w += 256) {
        s  += partials[(size_t)w * 128 + c];
        s2 += partials[(size_t)w * 128 + 64 + c];
    }
#pragma unroll
    for (int off = 1; off < 64; off <<= 1) {
        s  += __shfl_xor(s, off, 64);
        s2 += __shfl_xor(s2, off, 64);
    }
    __shared__ float sm[8];
    int wv = t >> 6, ln = t & 63;
    if (ln == 0) { sm[wv] = s; sm[4 + wv] = s2; }
    __syncthreads();
    if (t == 0) {
        float S  = sm[0] + sm[1] + sm[2] + sm[3];
        float S2 = sm[4] + sm[5] + sm[6] + sm[7];
        const float invN = 1.0f / (float)N_PTS;
        float mu = S * invN;
        float var = S2 * invN - mu * mu;
        float sc = gamma[c] * rsqrtf(var + 1e-4f);
        scsh[c] = sc;
        scsh[64 + c] = beta[c] - mu * sc;
    }
}

// ---------------- BN + ReLU -> bf16 (input to next conv) ----------------
__global__ void bn_relu_cast_k(const unsigned short* __restrict__ ybf, const float* __restrict__ scsh,
                               unsigned short* __restrict__ xb) {
    int t = blockIdx.x * 256 + threadIdx.x;
    if (t >= TOTAL / 8) return;
    int i = t * 8;
    int c0 = i & 63;
    u16x8 v = *(const u16x8*)(ybf + i);
    f32x4 sa = *(const f32x4*)(scsh + c0);
    f32x4 sb = *(const f32x4*)(scsh + c0 + 4);
    f32x4 ba = *(const f32x4*)(scsh + 64 + c0);
    f32x4 bb = *(const f32x4*)(scsh + 64 + c0 + 4);
    u16x8 o;
#pragma unroll
    for (int j = 0; j < 4; ++j) {
        o[j]     = f2bf(fmaxf(bf2f(v[j])     * sa[j] + ba[j], 0.f));
        o[4 + j] = f2bf(fmaxf(bf2f(v[4 + j]) * sb[j] + bb[j], 0.f));
    }
    *(u16x8*)(xb + i) = o;
}

// ---------------- BN + residual + ReLU -> f32 out (+ bf16 for next conv) ----------------
__global__ void bn_add_relu_k(const unsigned short* __restrict__ ybf, const float* __restrict__ scsh,
                              const float* __restrict__ res, float* __restrict__ xout,
                              unsigned short* __restrict__ xb, int writeBf) {
    int t = blockIdx.x * 256 + threadIdx.x;
    if (t >= TOTAL / 8) return;
    int i = t * 8;
    int c0 = i & 63;
    u16x8 v = *(const u16x8*)(ybf + i);
    f32x4 q0 = ((const f32x4*)(res + i))[0];
    f32x4 q1 = ((const f32x4*)(res + i))[1];
    f32x4 sa = *(const f32x4*)(scsh + c0);
    f32x4 sb = *(const f32x4*)(scsh + c0 + 4);
    f32x4 ba = *(const f32x4*)(scsh + 64 + c0);
    f32x4 bb = *(const f32x4*)(scsh + 64 + c0 + 4);
    f32x4 o0, o1;
#pragma unroll
    for (int j = 0; j < 4; ++j) {
        o0[j] = fmaxf(bf2f(v[j])     * sa[j] + ba[j] + q0[j], 0.f);
        o1[j] = fmaxf(bf2f(v[4 + j]) * sb[j] + bb[j] + q1[j], 0.f);
    }
    ((f32x4*)(xout + i))[0] = o0;
    ((f32x4*)(xout + i))[1] = o1;
    if (writeBf) {
        u16x8 o;
#pragma unroll
        for (int j = 0; j < 4; ++j) { o[j] = f2bf(o0[j]); o[4 + j] = f2bf(o1[j]); }
        *(u16x8*)(xb + i) = o;
    }
}

extern "C" void kernel_launch(void* const* d_in, const int* in_sizes, int n_in,
                              void* d_out, int out_size, void* d_ws, size_t ws_size,
                              hipStream_t stream) {
    const float* feats = (const float*)d_in[0];
    const int*   nbrs  = (const int*)d_in[1];
    const float* W     = (const float*)d_in[2];
    const float* gamma = (const float*)d_in[3];
    const float* beta  = (const float*)d_in[4];
    float* out = (float*)d_out;

    char* ws = (char*)d_ws;
    unsigned short* xb       = (unsigned short*)ws;              // 12,800,128 B
    unsigned short* ybf      = (unsigned short*)(ws + 12800512); // 12,800,000 B
    unsigned short* Wp       = (unsigned short*)(ws + 25600512); //    884,736 B
    int*            nbrsT    = (int*)(ws + 26485248);            // 10,810,368 B
    float*          partials = (float*)(ws + 37295616);          //    400,384 B
    float*          scsh     = (float*)(ws + 37696000);          //        512 B

    dim3 b256(256);
    cast_in_k<<<((N_PTS + 1) * 8 + 255) / 256, b256, 0, stream>>>(feats, xb);
    tr_nbrs_k<<<NT_STRIDE / 64, b256, 0, stream>>>(nbrs, nbrsT);
    pack_w_k<<<(4 * NK * 4096) / 256, b256, 0, stream>>>(W, Wp);

    const int appl_blocks = (TOTAL / 8) / 256;  // 3125
    for (int blk = 0; blk < 2; ++blk) {
        int c0 = blk * 2, c1 = blk * 2 + 1;
        conv_k<<<NB_CONV, b256, 0, stream>>>(xb, nbrsT, Wp + (size_t)c0 * NK * 4096, ybf, partials);
        bn_fin_k<<<64, b256, 0, stream>>>(partials, gamma + c0 * 64, beta + c0 * 64, scsh);
        bn_relu_cast_k<<<appl_blocks, b256, 0, stream>>>(ybf, scsh, xb);
        conv_k<<<NB_CONV, b256, 0, stream>>>(xb, nbrsT, Wp + (size_t)c1 * NK * 4096, ybf, partials);
        bn_fin_k<<<64, b256, 0, stream>>>(partials, gamma + c1 * 64, beta + c1 * 64, scsh);
        const float* res = (blk == 0) ? feats : (const float*)out;
        bn_add_relu_k<<<appl_blocks, b256, 0, stream>>>(ybf, scsh, res, out, xb, blk == 0 ? 1 : 0);
    }
}